// Round 2
// 297.340 us; speedup vs baseline: 1.0145x; 1.0145x over previous
//
#include <hip/hip_runtime.h>
#include <hip/hip_bf16.h>
#include <stdint.h>

// Problem constants (fixed by setup_inputs)
#define NE   8
#define DOUT 2048
#define DIN  2048
#define SEQ  8192
#define GSZ  128
#define FP8_MAX 448.0f
#define EPSQ 1e-12f

typedef float f32x4  __attribute__((ext_vector_type(4)));
typedef float f32x16 __attribute__((ext_vector_type(16)));
typedef int   i32x4  __attribute__((ext_vector_type(4)));
typedef int   i32x8  __attribute__((ext_vector_type(8)));

// async global->LDS, 16B/lane. LDS dest = wave-uniform base (+lane*16 by HW);
// global src may be per-lane.
__device__ __forceinline__ void async16(void* lds_base, const void* gptr) {
    __builtin_amdgcn_global_load_lds(
        (const __attribute__((address_space(1))) unsigned int*)gptr,
        (__attribute__((address_space(3))) unsigned int*)lds_base,
        16, 0, 0);
}

// ---------------------------------------------------------------------------
// Kernel 1: per-1x128-tile quant of x. One float4 per thread; each 32-lane
// half-wave group covers one tile. Coalesced float4 loads, dword stores.
__global__ __launch_bounds__(256) void quant_x_kernel(
    const float* __restrict__ x, unsigned char* __restrict__ qx,
    float* __restrict__ sx)
{
    const int g = blockIdx.x * 256 + threadIdx.x;   // float4 group index
    const float4 v = ((const float4*)x)[g];
    float a = fmaxf(fmaxf(fabsf(v.x), fabsf(v.y)),
                    fmaxf(fabsf(v.z), fabsf(v.w)));
    #pragma unroll
    for (int o = 16; o; o >>= 1) a = fmaxf(a, __shfl_xor(a, o));  // 32-lane tile
    const float scale = fmaxf(a, EPSQ) / FP8_MAX;
    const int tile = g >> 5;                        // == row*16 + kb
    if ((threadIdx.x & 31) == 0) sx[tile] = scale;

    float q0 = fminf(fmaxf(v.x / scale, -FP8_MAX), FP8_MAX);
    float q1 = fminf(fmaxf(v.y / scale, -FP8_MAX), FP8_MAX);
    float q2 = fminf(fmaxf(v.z / scale, -FP8_MAX), FP8_MAX);
    float q3 = fminf(fmaxf(v.w / scale, -FP8_MAX), FP8_MAX);
    int lo = __builtin_amdgcn_cvt_pk_fp8_f32(q0, q1, 0, false);
    int pk = __builtin_amdgcn_cvt_pk_fp8_f32(q2, q3, lo, true);
    ((unsigned int*)qx)[g] = (unsigned int)pk;
}

// ---------------------------------------------------------------------------
// Kernel 2: per-128x128-block quant of w. Stage block into 64 KB LDS via
// global_load_lds, amax from LDS, quantize from LDS.
__global__ __launch_bounds__(256) void quant_w_kernel(
    const float* __restrict__ w, unsigned char* __restrict__ qw,
    float* __restrict__ sw)
{
    __shared__ float buf[128 * 128];   // 64 KB
    __shared__ float red[4];

    const int cb = blockIdx.x;   // din block 0..15
    const int rb = blockIdx.y;   // dout block 0..15
    const int e  = blockIdx.z;   // expert 0..7
    const int t  = threadIdx.x;
    const int lane = t & 63, wv = t >> 6;

    const size_t base = ((size_t)e * DOUT + rb * GSZ) * DIN + cb * GSZ;
    const float* wp = w + base;

    // stage 64 KB: 4 waves x 16 iters x 1 KB. 32 sixteen-byte chunks per row.
    #pragma unroll
    for (int j = 0; j < 16; ++j) {
        int f16 = (wv * 16 + j) * 64 + lane;     // 16-byte chunk index 0..4095
        int row = f16 >> 5, cc = f16 & 31;
        async16(buf + (wv * 16 + j) * 256,
                wp + (size_t)row * DIN + cc * 4);
    }
    __syncthreads();

    float a = 0.f;
    #pragma unroll
    for (int i = 0; i < 16; ++i) {
        f32x4 v = *(const f32x4*)(buf + (t + i * 256) * 4);
        a = fmaxf(a, fmaxf(fmaxf(fabsf(v[0]), fabsf(v[1])),
                           fmaxf(fabsf(v[2]), fabsf(v[3]))));
    }
    #pragma unroll
    for (int o = 32; o; o >>= 1) a = fmaxf(a, __shfl_xor(a, o));
    if (lane == 0) red[wv] = a;
    __syncthreads();
    a = fmaxf(fmaxf(red[0], red[1]), fmaxf(red[2], red[3]));
    const float scale = fmaxf(a, EPSQ) / FP8_MAX;
    if (t == 0) sw[(e * 16 + rb) * 16 + cb] = scale;

    unsigned int* qout = (unsigned int*)(qw + base);
    #pragma unroll
    for (int i = 0; i < 16; ++i) {
        int idx = t + i * 256;
        f32x4 v = *(const f32x4*)(buf + idx * 4);
        float q0 = fminf(fmaxf(v[0] / scale, -FP8_MAX), FP8_MAX);
        float q1 = fminf(fmaxf(v[1] / scale, -FP8_MAX), FP8_MAX);
        float q2 = fminf(fmaxf(v[2] / scale, -FP8_MAX), FP8_MAX);
        float q3 = fminf(fmaxf(v[3] / scale, -FP8_MAX), FP8_MAX);
        int lo = __builtin_amdgcn_cvt_pk_fp8_f32(q0, q1, 0, false);
        int pk = __builtin_amdgcn_cvt_pk_fp8_f32(q2, q3, lo, true);
        int r = idx >> 5, c4 = idx & 31;
        qout[r * (DIN / 4) + c4] = (unsigned int)pk;
    }
}

// ---------------------------------------------------------------------------
// Kernel 3: grouped fp8 GEMM via MX-scaled MFMA (32x32x64 f8f6f4, fmt=fp8,
// unit e8m0 scales = 0x7F -> 2^0) at ~2.1x the non-scaled fp8 issue rate.
// Our own per-128-block f32 scaling is applied exactly as before via the
// telescoped in-place rescale:
//   out[s,n] = c[s,15]*A15,  A_j = A_{j-1}*r_j + P_j,  r_j = c[s,j-1]/c[s,j],
//   c[s,j] = sx[s,j]*sw[e,nb,j]  (one scale per 128-k block per 128-col block)
// Rs[kb][row] holds r_kb for kb>=1; Rs[0][row] holds the final scale c[.,15].
// LDS tiles XOR-swizzled on 16B chunks (pos = chunk ^ (row&7)); a lane's 32B
// fragment = two ds_read_b128 at chunk c = ks*4 + (lane>>5)*2 + {0,1}.
// 32x32 C/D layout: col = lane&31, row = (reg&3) + 8*(reg>>2) + 4*(lane>>5).
// A/B fragment: row = lane&31, k = (lane>>5)*32 + byte.
// LDS total = 32 KB tiles + 8 KB Rs = 40 KB -> 4 blocks/CU; grid 1024 = 256*4.
__global__ __launch_bounds__(256, 4) void gemm_kernel(
    const unsigned char* __restrict__ qx, const float* __restrict__ sx,
    const unsigned char* __restrict__ qw, const float* __restrict__ sw,
    const int* __restrict__ tpe, float* __restrict__ out)
{
    __shared__ unsigned char Asm[128 * 128];
    __shared__ unsigned char Bsm[128 * 128];
    __shared__ float Rs[16 * 128];   // [kb][row]

    const int tid  = threadIdx.x;
    const int lane = tid & 63;
    const int wv   = tid >> 6;
    const int wm   = wv >> 1, wn = wv & 1;
    const int l31  = lane & 31;
    const int h    = lane >> 5;
    const int nb   = blockIdx.x;      // 0..15
    const int mb   = blockIdx.y;      // 0..63
    const int r0   = mb * 128, n0 = nb * 128;

    int e = -1, start = 0;
    #pragma unroll
    for (int i = 0; i < NE; ++i) {
        int end = start + tpe[i];
        if (r0 >= start && r0 < end) e = i;
        start = end;
    }
    if (e < 0) {
        f32x4 z = {0.f, 0.f, 0.f, 0.f};
        for (int i = tid; i < 128 * 32; i += 256) {
            int r = i >> 5, c4 = i & 31;
            *(f32x4*)(out + (size_t)(r0 + r) * DOUT + n0 + c4 * 4) = z;
        }
        return;
    }

    // ---- prologue: c = sx*sw into Asm scratch, then ratios into Rs ----
    {
        float* Cs = (float*)Asm;              // 8 KB scratch inside A tile
        const float* sp  = sx + (size_t)r0 * 16;
        const float* swp = sw + (e * 16 + nb) * 16;
        for (int i = tid; i < 2048; i += 256) {
            int r = i >> 4, kb = i & 15;
            Cs[kb * 128 + r] = sp[i] * swp[kb];
        }
        __syncthreads();
        float rv[8];
        #pragma unroll
        for (int j = 0; j < 8; ++j) {
            int i = tid + j * 256;
            int kb = i >> 7, row = i & 127;
            rv[j] = (kb == 0) ? Cs[15 * 128 + row]
                              : Cs[(kb - 1) * 128 + row] / Cs[kb * 128 + row];
        }
        #pragma unroll
        for (int j = 0; j < 8; ++j) Rs[tid + j * 256] = rv[j];
        // loop-top __syncthreads() orders: Cs reads done before Asm staging,
        // Rs writes visible before first rescale use (kb=1).
    }

    const unsigned char* Ag = qx + (size_t)r0 * DIN;
    const unsigned char* Bg = qw + (size_t)e * DOUT * DIN + (size_t)n0 * DIN;

    // staging source indices (per-lane, loop-invariant)
    int srow[4], scol[4];
    #pragma unroll
    for (int j = 0; j < 4; ++j) {
        int f = wv * 4096 + j * 1024 + lane * 16;
        int row = f >> 7, pc = (f >> 4) & 7;
        srow[j] = row;
        scol[j] = (pc ^ (row & 7)) * 16;
    }

    // fragment read bases: A row = wm*64 + mi*32 + l31, B row = wn*64 + ni*32 + l31
    int abase[2], ax8[2], bbase[2], bx8[2];
    #pragma unroll
    for (int i = 0; i < 2; ++i) {
        int ra = wm * 64 + i * 32 + l31;
        abase[i] = ra * 128; ax8[i] = ra & 7;
        int rb = wn * 64 + i * 32 + l31;
        bbase[i] = rb * 128; bx8[i] = rb & 7;
    }

    f32x16 acc[2][2];
    #pragma unroll
    for (int mi = 0; mi < 2; ++mi)
        #pragma unroll
        for (int ni = 0; ni < 2; ++ni)
            #pragma unroll
            for (int q = 0; q < 16; ++q) acc[mi][ni][q] = 0.f;

    for (int kb = 0; kb < 16; ++kb) {
        __syncthreads();
        #pragma unroll
        for (int j = 0; j < 4; ++j) {
            async16(Asm + wv * 4096 + j * 1024,
                    Ag + (size_t)srow[j] * DIN + kb * GSZ + scol[j]);
            async16(Bsm + wv * 4096 + j * 1024,
                    Bg + (size_t)srow[j] * DIN + kb * GSZ + scol[j]);
        }
        __syncthreads();

        if (kb) {   // rescale accumulators into this k-block's units
            #pragma unroll
            for (int mi = 0; mi < 2; ++mi) {
                const float* rp = Rs + kb * 128 + wm * 64 + mi * 32 + 4 * h;
                f32x4 rr[4];
                #pragma unroll
                for (int g = 0; g < 4; ++g) rr[g] = *(const f32x4*)(rp + 8 * g);
                #pragma unroll
                for (int ni = 0; ni < 2; ++ni)
                    #pragma unroll
                    for (int g = 0; g < 4; ++g)
                        #pragma unroll
                        for (int j = 0; j < 4; ++j)
                            acc[mi][ni][g * 4 + j] *= rr[g][j];
            }
        }

        #pragma unroll
        for (int ks = 0; ks < 2; ++ks) {
            const int c0 = ks * 4 + h * 2;
            i32x8 A[2], B[2];
            #pragma unroll
            for (int i = 0; i < 2; ++i) {
                i32x4 alo = *(const i32x4*)(Asm + abase[i] + ((c0    ) ^ ax8[i]) * 16);
                i32x4 ahi = *(const i32x4*)(Asm + abase[i] + ((c0 + 1) ^ ax8[i]) * 16);
                i32x4 blo = *(const i32x4*)(Bsm + bbase[i] + ((c0    ) ^ bx8[i]) * 16);
                i32x4 bhi = *(const i32x4*)(Bsm + bbase[i] + ((c0 + 1) ^ bx8[i]) * 16);
                #pragma unroll
                for (int q = 0; q < 4; ++q) {
                    A[i][q] = alo[q]; A[i][q + 4] = ahi[q];
                    B[i][q] = blo[q]; B[i][q + 4] = bhi[q];
                }
            }
            #pragma unroll
            for (int mi = 0; mi < 2; ++mi)
                #pragma unroll
                for (int ni = 0; ni < 2; ++ni)
                    acc[mi][ni] = __builtin_amdgcn_mfma_scale_f32_32x32x64_f8f6f4(
                        A[mi], B[ni], acc[mi][ni],
                        0, 0,                       // cbsz=fp8, blgp=fp8
                        0, 0x7f7f7f7f,              // A scale: e8m0 1.0
                        0, 0x7f7f7f7f);             // B scale: e8m0 1.0
        }
    }

    // epilogue: apply final scale (Rs kb=0 slot).
    // C/D: col = l31, row = (reg&3) + 8*(reg>>2) + 4*h
    #pragma unroll
    for (int mi = 0; mi < 2; ++mi) {
        const float* fp = Rs + wm * 64 + mi * 32 + 4 * h;
        f32x4 fv[4];
        #pragma unroll
        for (int g = 0; g < 4; ++g) fv[g] = *(const f32x4*)(fp + 8 * g);
        const int rbase = r0 + wm * 64 + mi * 32 + 4 * h;
        #pragma unroll
        for (int ni = 0; ni < 2; ++ni) {
            const int col = n0 + wn * 64 + ni * 32 + l31;
            #pragma unroll
            for (int g = 0; g < 4; ++g)
                #pragma unroll
                for (int j = 0; j < 4; ++j)
                    out[(size_t)(rbase + 8 * g + j) * DOUT + col] =
                        acc[mi][ni][g * 4 + j] * fv[g][j];
        }
    }
}

// ---------------------------------------------------------------------------
extern "C" void kernel_launch(void* const* d_in, const int* in_sizes, int n_in,
                              void* d_out, int out_size, void* d_ws, size_t ws_size,
                              hipStream_t stream) {
    const float* x   = (const float*)d_in[0];   // [8192, 2048] fp32
    const float* wt  = (const float*)d_in[1];   // [16384, 2048] fp32
    const int*   tpe = (const int*)d_in[2];     // [8]
    float* out = (float*)d_out;                 // [8192, 2048] fp32

    char* ws = (char*)d_ws;
    unsigned char* qx = (unsigned char*)ws;                       // 16 MB
    unsigned char* qw = qx + (size_t)SEQ * DIN;                   // 32 MB
    float* sx = (float*)(qw + (size_t)NE * DOUT * DIN);           // 512 KB
    float* sw = sx + (size_t)SEQ * 16;                            // 4 KB

    quant_x_kernel<<<SEQ * DIN / 4 / 256, 256, 0, stream>>>(x, qx, sx);
    quant_w_kernel<<<dim3(16, 16, NE), 256, 0, stream>>>(wt, qw, sw);
    gemm_kernel<<<dim3(DOUT / 128, SEQ / 128), 256, 0, stream>>>(
        qx, sx, qw, sw, tpe, out);
}